// Round 1
// baseline (736.588 us; speedup 1.0000x reference)
//
#include <hip/hip_runtime.h>

// Problem constants (B=2, H=16, L=2048, D=64 — fixed by the reference setup).
#define BH   32
#define LSEQ 2048
#define DDIM 64
#define ERRC 1e-12f

typedef __attribute__((ext_vector_type(8))) short  bf16x8;
typedef __attribute__((ext_vector_type(4))) float  floatx4;
typedef __attribute__((ext_vector_type(4))) unsigned short ushort4v;

// float -> bf16 round-to-nearest-even (inputs are finite, no NaN handling needed)
__device__ __forceinline__ unsigned short f2bf(float f) {
    unsigned u = __float_as_uint(f);
    u = u + 0x7FFFu + ((u >> 16) & 1u);
    return (unsigned short)(u >> 16);
}

__device__ __forceinline__ bf16x8 pack8(const float* __restrict__ p) {
    const floatx4* pv = (const floatx4*)p;
    floatx4 x = pv[0], y = pv[1];
    bf16x8 r;
    r[0] = (short)f2bf(x[0]); r[1] = (short)f2bf(x[1]);
    r[2] = (short)f2bf(x[2]); r[3] = (short)f2bf(x[3]);
    r[4] = (short)f2bf(y[0]); r[5] = (short)f2bf(y[1]);
    r[6] = (short)f2bf(y[2]); r[7] = (short)f2bf(y[3]);
    return r;
}

// Prep: k (fp32) -> ksb (bf16), 4,194,304 elements, 4 per thread.
__global__ __launch_bounds__(256) void prep_bf16(const float* __restrict__ k,
                                                 unsigned short* __restrict__ ksb) {
    int idx4 = blockIdx.x * 256 + threadIdx.x;
    floatx4 v = ((const floatx4*)k)[idx4];
    ushort4v o;
    o[0] = f2bf(v[0]); o[1] = f2bf(v[1]); o[2] = f2bf(v[2]); o[3] = f2bf(v[3]);
    ((ushort4v*)ksb)[idx4] = o;
}

// DPP row_shr:<N> add with zero-fill — one Hillis-Steele scan step over 16-lane rows.
template<int CTRL>
__device__ __forceinline__ float scan_step(float x) {
    int s = __builtin_amdgcn_update_dpp(0, __float_as_int(x), CTRL, 0xF, 0xF, true);
    return x + __int_as_float(s);
}

template<bool RAW>
__device__ __forceinline__ void load_btile(const void* __restrict__ kp, long base,
                                           int j0, int l16, int q,
                                           const float* __restrict__ dest, int bhL,
                                           bf16x8& b0, bf16x8& b1, float& dv) {
    const int brow = j0 + l16;
    if (RAW) {
        const float* p = (const float*)kp + base + (long)brow * DDIM + q * 8;
        b0 = pack8(p);
        b1 = pack8(p + 32);
    } else {
        const unsigned short* p = (const unsigned short*)kp + base + (long)brow * DDIM + q * 8;
        b0 = *(const bf16x8*)p;
        b1 = *(const bf16x8*)(p + 32);
    }
    dv = dest[bhL + brow];
}

// One wave = one 16-row i-tile; streams 128 j-tiles of 16 columns.
// MFMA 16x16x32 bf16: A[m=lane&15][k=quad*8+t], B[k=quad*8+t][n=lane&15],
// C/D: col=lane&15, row=quad*4+reg.
template<bool RAW>
__global__ __launch_bounds__(256) void mha_fused(const void* __restrict__ kp,
                                                 const float* __restrict__ src,
                                                 const float* __restrict__ dest,
                                                 float* __restrict__ out) {
    const int tid  = threadIdx.x;
    const int wave = tid >> 6;
    const int lane = tid & 63;
    const int q    = lane >> 4;
    const int l16  = lane & 15;
    // bh in low bits: same-bh blocks are 32 apart -> same XCD under mod-8 dispatch.
    const int bh = blockIdx.x & 31;
    const int ib = blockIdx.x >> 5;          // 0..31
    const int i0 = (ib * 4 + wave) * 16;     // this wave's 16-row tile
    const int bhL = bh * LSEQ;
    const long base = (long)bh * LSEQ * DDIM;

    // A fragments (held for the whole kernel)
    bf16x8 a0, a1;
    {
        const int arow = i0 + l16;
        if (RAW) {
            const float* p = (const float*)kp + base + (long)arow * DDIM + q * 8;
            a0 = pack8(p);
            a1 = pack8(p + 32);
        } else {
            const unsigned short* p = (const unsigned short*)kp + base + (long)arow * DDIM + q * 8;
            a0 = *(const bf16x8*)p;
            a1 = *(const bf16x8*)(p + 32);
        }
    }

    // sqrt-scaled source weights for this lane's 4 output rows
    float s_r[4];
#pragma unroll
    for (int r = 0; r < 4; ++r)
        s_r[r] = sqrtf(src[bhL + i0 + q * 4 + r] + ERRC);

    float carry[4] = {0.f, 0.f, 0.f, 0.f};

    bf16x8 b0, b1;
    float dv;
    load_btile<RAW>(kp, base, 0, l16, q, dest, bhL, b0, b1, dv);

    const float twothirds = 2.0f / 3.0f;

    for (int jt = 0; jt < 128; ++jt) {
        const int j0 = jt << 4;
        // prefetch next tile (clamped redundant load on last iter)
        bf16x8 nb0, nb1;
        float ndv;
        const int jn = (jt < 127) ? (jt + 1) : 127;
        load_btile<RAW>(kp, base, jn << 4, l16, q, dest, bhL, nb0, nb1, ndv);

        floatx4 acc = {0.f, 0.f, 0.f, 0.f};
        acc = __builtin_amdgcn_mfma_f32_16x16x32_bf16(a0, b0, acc, 0, 0, 0);
        acc = __builtin_amdgcn_mfma_f32_16x16x32_bf16(a1, b1, acc, 0, 0, 0);

        const float dj = sqrtf(dv + ERRC);   // column weight (indexed by l16)

        float t[4];
#pragma unroll
        for (int r = 0; r < 4; ++r) {
            float v = acc[r] * (s_r[r] * dj);     // a1[i][j] in fp32
            v = fmaxf(v, 0.f) + ERRC;             // relu, +err
            t[r] = exp2f(twothirds * __log2f(v)); // ^(2/3)
        }

        // inclusive scan over the 16 columns (lanes sharing quad), pure-VALU DPP
#pragma unroll
        for (int r = 0; r < 4; ++r) {
            t[r] = scan_step<0x111>(t[r]);  // row_shr:1
            t[r] = scan_step<0x112>(t[r]);  // row_shr:2
            t[r] = scan_step<0x114>(t[r]);  // row_shr:4
            t[r] = scan_step<0x118>(t[r]);  // row_shr:8
            t[r] += carry[r];
            carry[r] = __shfl(t[r], 15, 16); // running row sum through this tile
        }

        // masked store: keep j >= i, else 0 (must write everything — out is poisoned)
#pragma unroll
        for (int r = 0; r < 4; ++r) {
            const int irow = i0 + q * 4 + r;
            const int j    = j0 + l16;
            const float v  = (j >= irow) ? t[r] : 0.f;
            __builtin_nontemporal_store(v, &out[(long)(bhL + irow) * LSEQ + j]);
        }

        b0 = nb0; b1 = nb1; dv = ndv;
    }
}

extern "C" void kernel_launch(void* const* d_in, const int* in_sizes, int n_in,
                              void* d_out, int out_size, void* d_ws, size_t ws_size,
                              hipStream_t stream) {
    const float* k    = (const float*)d_in[0];
    const float* src  = (const float*)d_in[1];
    const float* dest = (const float*)d_in[2];
    float* out = (float*)d_out;

    const size_t needed = (size_t)BH * LSEQ * DDIM * sizeof(unsigned short); // 8 MiB
    if (ws_size >= needed) {
        unsigned short* ksb = (unsigned short*)d_ws;
        prep_bf16<<<dim3(4096), dim3(256), 0, stream>>>(k, ksb);
        mha_fused<false><<<dim3(1024), dim3(256), 0, stream>>>(ksb, src, dest, out);
    } else {
        mha_fused<true><<<dim3(1024), dim3(256), 0, stream>>>(k, src, dest, out);
    }
}